// Round 16
// baseline (194.233 us; speedup 1.0000x reference)
//
#include <hip/hip_runtime.h>
#include <math.h>

#define CC 256
#define LL 8192
#define RR 32
#define PPP 256
#define NTOP 4
#define TOKS 16384
#define TBLK (TOKS * 32)   // per-kb stride for token-row operands

typedef unsigned short u16;
typedef __attribute__((ext_vector_type(8))) short short8;
typedef __attribute__((ext_vector_type(8))) unsigned short u16x8;
typedef __attribute__((ext_vector_type(4))) float f32x4;
typedef __attribute__((ext_vector_type(4))) unsigned short u16x4;

#if defined(__has_builtin)
#if __has_builtin(__builtin_amdgcn_exp2f)
#define EXP2(x) __builtin_amdgcn_exp2f(x)
#endif
#endif
#ifndef EXP2
#define EXP2(x) exp2f(x)
#endif

__device__ inline u16 f2bf(float f) {
  unsigned int b = __float_as_uint(f);
  unsigned int r = (b + 0x7FFFu + ((b >> 16) & 1u)) >> 16;
  return (u16)r;
}
__device__ inline float bf2f(u16 x) { return __uint_as_float(((unsigned int)x) << 16); }

// ---------------- BN stats (branch 1 only) ----------------
__global__ __launch_bounds__(256) void k_bnstats(const float* __restrict__ x,
                                                 float* __restrict__ mean,
                                                 float* __restrict__ istd) {
  int c = blockIdx.x, tid = threadIdx.x;
  float s = 0.f, sq = 0.f;
  for (int i = tid; i < 2 * LL / 4; i += 256) {
    int t = i >> 11, l4 = (i & 2047) * 4;
    float4 v = *(const float4*)&x[(size_t)(t * CC + c) * LL + l4];
    s += (v.x + v.y) + (v.z + v.w);
    sq += (v.x * v.x + v.y * v.y) + (v.z * v.z + v.w * v.w);
  }
  __shared__ float rs[256], rq[256];
  rs[tid] = s; rq[tid] = sq;
  __syncthreads();
  for (int off = 128; off > 0; off >>= 1) {
    if (tid < off) { rs[tid] += rs[tid + off]; rq[tid] += rq[tid + off]; }
    __syncthreads();
  }
  if (tid == 0) {
    float m = rs[0] * (1.f / (2 * LL));
    float var = rq[0] * (1.f / (2 * LL)) - m * m;
    mean[c] = m;
    istd[c] = rsqrtf(var + 1e-5f);
  }
}

// ---------------- finish BN2 stats from per-block partials (deterministic) ----------------
__global__ __launch_bounds__(128) void k_bnfin(const float* __restrict__ psum,
                                               const float* __restrict__ psq,
                                               float* __restrict__ mean,
                                               float* __restrict__ istd) {
  int c = blockIdx.x;
  int tid = threadIdx.x;
  __shared__ float rs[128], rq[128];
  rs[tid] = psum[c * 128 + tid];
  rq[tid] = psq[c * 128 + tid];
  __syncthreads();
  for (int off = 64; off > 0; off >>= 1) {
    if (tid < off) { rs[tid] += rs[tid + off]; rq[tid] += rq[tid + off]; }
    __syncthreads();
  }
  if (tid == 0) {
    float m = rs[0] * (1.f / 16384.f);
    float var = rq[0] * (1.f / 16384.f) - m * m;
    mean[c] = m;
    istd[c] = rsqrtf(var + 1e-5f);
  }
}

// ---------------- fused BN + 2-step LIF + transpose -> actT bf16 K-blocked [kb][token][32] ----------------
__global__ __launch_bounds__(256) void k_lifT(const float* __restrict__ xin,
                                              const float* __restrict__ mean,
                                              const float* __restrict__ istd,
                                              const float* __restrict__ g,
                                              const float* __restrict__ b,
                                              u16* __restrict__ actT) {
  __shared__ float t0[32][33], t1[32][33];
  int l0 = blockIdx.x * 32, c0 = blockIdx.y * 32;
  int tx = threadIdx.x & 31, ty = threadIdx.x >> 5;
  for (int i = 0; i < 32; i += 8) {
    int c = c0 + ty + i;
    float m = mean[c], is = istd[c], gg = g[c], bb = b[c];
    float x0 = xin[(size_t)c * LL + l0 + tx];
    float x1 = xin[(size_t)(CC + c) * LL + l0 + tx];
    float y0 = gg * (x0 - m) * is + bb;
    float y1 = gg * (x1 - m) * is + bb;
    float v = y0 * 0.5f;
    float s0 = (v >= 1.f) ? 1.f : 0.f;
    v -= s0;
    v += (y1 - v) * 0.5f;
    float s1 = (v >= 1.f) ? 1.f : 0.f;
    t0[ty + i][tx] = s0;
    t1[ty + i][tx] = s1;
  }
  __syncthreads();
  size_t kb = (size_t)(c0 >> 5) * TBLK;
  for (int i = 0; i < 32; i += 8) {
    int l = l0 + ty + i;
    actT[kb + (size_t)l * 32 + tx] = f2bf(t0[tx][ty + i]);
    actT[kb + (size_t)(LL + l) * 32 + tx] = f2bf(t1[tx][ty + i]);
  }
}

// ---------------- fused weight transposes: fp32 [K][N] -> bf16 K-blocked [kb][n][32] ----------------
__device__ inline void tr_tile(const float* __restrict__ in, u16* __restrict__ out,
                               int C, int c0, int r0) {
  __shared__ float t[32][33];
  int tx = threadIdx.x & 31, ty = threadIdx.x >> 5;
  for (int i = 0; i < 32; i += 8)
    t[ty + i][tx] = in[(size_t)(r0 + ty + i) * C + c0 + tx];
  __syncthreads();
  size_t kb = (size_t)(r0 >> 5) * C * 32;
  for (int i = 0; i < 32; i += 8)
    out[kb + (size_t)(c0 + ty + i) * 32 + tx] = f2bf(t[tx][ty + i]);
}

__global__ __launch_bounds__(256) void k_trall(const float* __restrict__ wqkv,
                                               const float* __restrict__ w1,
                                               const float* __restrict__ w2,
                                               const float* __restrict__ wo,
                                               const float* __restrict__ lep,
                                               u16* __restrict__ wqkvT, u16* __restrict__ w1T,
                                               u16* __restrict__ w2T, u16* __restrict__ woT,
                                               float* __restrict__ wTlep) {
  int b = blockIdx.x;
  if (b < 192) {
    tr_tile(wqkv, wqkvT, 768, (b % 24) * 32, (b / 24) * 32);
  } else if (b < 448) {
    int i = b - 192;
    tr_tile(w1, w1T, 1024, (i % 32) * 32, (i / 32) * 32);
  } else if (b < 704) {
    int i = b - 448;
    tr_tile(w2, w2T, 256, (i % 8) * 32, (i / 8) * 32);
  } else if (b < 768) {
    int i = b - 704;
    tr_tile(wo, woT, 256, (i % 8) * 32, (i / 8) * 32);
  } else {
    int c = threadIdx.x;
    for (int tap = 0; tap < 27; ++tap) wTlep[tap * 256 + c] = lep[c * 27 + tap];
  }
}

// ---------------- MFMA core, K-blocked operands + register prefetch; explicit wave coords ----------------
template<int MR, int NR, int KTOT>
__device__ inline void mfma_core_w(const u16* __restrict__ A0, int sAb,
                                   const u16* __restrict__ B0, int sBb,
                                   int wr, int wc, f32x4 acc[MR][NR]) {
  int lane = threadIdx.x & 63;
  int u = lane & 15;
  int g8 = (lane >> 4) * 8;
  const u16* Ap = A0 + (wr * MR * 16 + u) * 32 + g8;
  const u16* Bp = B0 + (wc * NR * 16 + u) * 32 + g8;
  constexpr int NKB = KTOT >> 5;
  short8 aA[MR], bA[NR], aB[MR], bB[NR];
#pragma unroll
  for (int i = 0; i < MR; ++i) aA[i] = *(const short8*)(Ap + i * 512);
#pragma unroll
  for (int j = 0; j < NR; ++j) bA[j] = *(const short8*)(Bp + j * 512);
#pragma unroll
  for (int kb = 0; kb < NKB; kb += 2) {
    if (kb + 1 < NKB) {
#pragma unroll
      for (int i = 0; i < MR; ++i) aB[i] = *(const short8*)(Ap + (size_t)(kb + 1) * sAb + i * 512);
#pragma unroll
      for (int j = 0; j < NR; ++j) bB[j] = *(const short8*)(Bp + (size_t)(kb + 1) * sBb + j * 512);
    }
#pragma unroll
    for (int i = 0; i < MR; ++i)
#pragma unroll
      for (int j = 0; j < NR; ++j)
        acc[i][j] = __builtin_amdgcn_mfma_f32_16x16x32_bf16(aA[i], bA[j], acc[i][j], 0, 0, 0);
    if (kb + 2 < NKB) {
#pragma unroll
      for (int i = 0; i < MR; ++i) aA[i] = *(const short8*)(Ap + (size_t)(kb + 2) * sAb + i * 512);
#pragma unroll
      for (int j = 0; j < NR; ++j) bA[j] = *(const short8*)(Bp + (size_t)(kb + 2) * sBb + j * 512);
    }
    if (kb + 1 < NKB) {
#pragma unroll
      for (int i = 0; i < MR; ++i)
#pragma unroll
        for (int j = 0; j < NR; ++j)
          acc[i][j] = __builtin_amdgcn_mfma_f32_16x16x32_bf16(aB[i], bB[j], acc[i][j], 0, 0, 0);
    }
  }
}

// ---------------- qkv GEMM -> bf16 per-head q(scaled)/k, transposed v (u16x4 packed); bf16 v token-major ----------------
__global__ __launch_bounds__(256) void k_gqkv(const u16* __restrict__ spkT, const u16* __restrict__ wT,
                                              const float* __restrict__ bias,
                                              u16* __restrict__ qh, u16* __restrict__ kh,
                                              u16* __restrict__ vt, u16* __restrict__ vtok) {
  f32x4 acc[4][4] = {};
  int m0 = blockIdx.x * 128, n0 = blockIdx.y * 128;
  int w = threadIdx.x >> 6;
  mfma_core_w<4, 4, 256>(spkT + (size_t)m0 * 32, TBLK, wT + (size_t)n0 * 32, 768 * 32,
                         w >> 1, w & 1, acc);
  int lane = threadIdx.x & 63;
  int wr = w >> 1, wc = w & 1;
  int u = lane & 15;
  const float QSC = 0.255034865f;   // 32^-0.5 * log2(e)
#pragma unroll
  for (int i = 0; i < 4; ++i) {
    int token0 = m0 + wr * 64 + i * 16 + (lane >> 4) * 4;
    int l = token0 & (LL - 1), nb = token0 >> 13;
    int lt = l >> 10, lh = (l >> 5) & 31, lw = l & 31;
    int r = ((lt >> 2) * 4 + (lh >> 3)) * 4 + (lw >> 3);
    int p0 = ((lt & 3) * 8 + (lh & 7)) * 8 + (lw & 7);
    int nr = nb * RR + r;
#pragma unroll
    for (int j = 0; j < 4; ++j) {
      int ch = n0 + wc * 64 + j * 16 + u;
      int which = ch >> 8, c = ch & 255;
      int hh = c >> 5, dh = c & 31;
      size_t hb = ((size_t)nr * 8 + hh) * 8192;
      float bb = bias[ch];
      if (which == 0) {
#pragma unroll
        for (int reg = 0; reg < 4; ++reg)
          qh[hb + (p0 + reg) * 32 + dh] = f2bf((acc[i][j][reg] + bb) * QSC);
      } else if (which == 1) {
#pragma unroll
        for (int reg = 0; reg < 4; ++reg)
          kh[hb + (p0 + reg) * 32 + dh] = f2bf(acc[i][j][reg] + bb);
      } else {
        u16x4 pk;
#pragma unroll
        for (int reg = 0; reg < 4; ++reg) {
          u16 vb = f2bf(acc[i][j][reg] + bb);
          pk[reg] = vb;
          vtok[(size_t)(token0 + reg) * CC + c] = vb;
        }
        *(u16x4*)&vt[hb + dh * 256 + p0] = pk;
      }
    }
  }
}

// ---------------- region means: block per (nr, h) ----------------
__global__ __launch_bounds__(256) void k_means(const u16* __restrict__ qh, const u16* __restrict__ kh,
                                               float* __restrict__ qm, float* __restrict__ km) {
  int nrh = blockIdx.x;
  int nr = nrh >> 3, h = nrh & 7;
  int tid = threadIdx.x;
  int dh = tid & 31, pg = tid >> 5;
  size_t base = (size_t)nrh * 8192;
  float sq = 0.f, sk = 0.f;
  for (int p = pg * 32; p < pg * 32 + 32; ++p) {
    sq += bf2f(qh[base + p * 32 + dh]);
    sk += bf2f(kh[base + p * 32 + dh]);
  }
  __shared__ float rq[256], rk[256];
  rq[tid] = sq; rk[tid] = sk;
  __syncthreads();
  if (pg == 0) {
#pragma unroll
    for (int g = 1; g < 8; ++g) { sq += rq[g * 32 + dh]; sk += rk[g * 32 + dh]; }
    qm[nr * 256 + h * 32 + dh] = sq * (1.f / 256);
    km[nr * 256 + h * 32 + dh] = sk * (1.f / 256);
  }
}

// ---------------- routing top-4: 8 lanes per candidate region ----------------
__global__ __launch_bounds__(256) void k_route(const float* __restrict__ qm,
                                               const float* __restrict__ km,
                                               int* __restrict__ idx) {
  int nr = blockIdx.x;
  int n = nr >> 5;
  int tid = threadIdx.x;
  int s = tid >> 3, cg = tid & 7;
  const float* qrow = qm + nr * CC;
  const float* krow = km + (n * RR + s) * CC;
  float sum = 0.f;
  for (int c = cg * 32; c < cg * 32 + 32; ++c) sum += qrow[c] * krow[c];
  sum += __shfl_xor(sum, 1);
  sum += __shfl_xor(sum, 2);
  sum += __shfl_xor(sum, 4);
  __shared__ float ar[32];
  if (cg == 0) ar[s] = sum;
  __syncthreads();
  if (tid == 0) {
    for (int t = 0; t < NTOP; ++t) {
      float best = -1e30f; int bi = 0;
      for (int ss = 0; ss < 32; ++ss)
        if (ar[ss] > best) { best = ar[ss]; bi = ss; }
      ar[bi] = -1e30f;
      idx[nr * NTOP + t] = bi;
    }
  }
}

// ---------------- MFMA flash attention: block (h, r, n), 4 waves x 64 q-rows ----------------
__global__ __launch_bounds__(256) void k_attn_mfma(const u16* __restrict__ qh,
                                                   const u16* __restrict__ kh,
                                                   const u16* __restrict__ vt,
                                                   const int* __restrict__ idx,
                                                   u16* __restrict__ oreg) {
  int h = blockIdx.x, r = blockIdx.y, n = blockIdx.z;
  int nr = n * RR + r;
  int lane = threadIdx.x & 63;
  int w = threadIdx.x >> 6;
  int u = lane & 15, g = lane >> 4;
  int swz = (u >> 1) & 3;
  __shared__ __align__(16) unsigned pl[4096];
  unsigned* plw = &pl[w * 1024];

  const u16* qb = qh + ((size_t)nr * 8 + h) * 8192;
  int q0 = w * 64;
  short8 qf[4];
#pragma unroll
  for (int f = 0; f < 4; ++f)
    qf[f] = *(const short8*)(qb + (size_t)(q0 + f * 16 + u) * 32 + g * 8);

  f32x4 accO[2][4] = {};
  float lsum[4] = {0.f, 0.f, 0.f, 0.f};
  const int* idxp = &idx[nr * NTOP];

  for (int ri = 0; ri < NTOP; ++ri) {
    int reg = idxp[ri];
    size_t rb = ((size_t)(n * RR + reg) * 8 + h) * 8192;
#pragma unroll 2
    for (int t = 0; t < 8; ++t) {
      int pb = t * 32;
      short8 kf0 = *(const short8*)(kh + rb + (size_t)(pb + u) * 32 + g * 8);
      short8 kf1 = *(const short8*)(kh + rb + (size_t)(pb + 16 + u) * 32 + g * 8);
      short8 vf0 = *(const short8*)(vt + rb + (size_t)u * 256 + pb + g * 8);
      short8 vf1 = *(const short8*)(vt + rb + (size_t)(16 + u) * 256 + pb + g * 8);

      f32x4 s0[4], s1[4];
      __builtin_amdgcn_s_setprio(1);
#pragma unroll
      for (int nf = 0; nf < 4; ++nf) {
        s0[nf] = __builtin_amdgcn_mfma_f32_16x16x32_bf16(kf0, qf[nf], (f32x4){0.f, 0.f, 0.f, 0.f}, 0, 0, 0);
        s1[nf] = __builtin_amdgcn_mfma_f32_16x16x32_bf16(kf1, qf[nf], (f32x4){0.f, 0.f, 0.f, 0.f}, 0, 0, 0);
      }
      __builtin_amdgcn_s_setprio(0);
#pragma unroll
      for (int nf = 0; nf < 4; ++nf) {
#pragma unroll
        for (int mf = 0; mf < 2; ++mf) {
          f32x4 sv = mf ? s1[nf] : s0[nf];
          float p0 = EXP2(sv[0]);
          float p1 = EXP2(sv[1]);
          float p2 = EXP2(sv[2]);
          float p3 = EXP2(sv[3]);
          lsum[nf] += (p0 + p1) + (p2 + p3);
          unsigned wA, wB;
          asm("v_cvt_pk_bf16_f32 %0, %1, %2" : "=v"(wA) : "v"(p0), "v"(p1));
          asm("v_cvt_pk_bf16_f32 %0, %1, %2" : "=v"(wB) : "v"(p2), "v"(p3));
          int bidx = (mf * 2 + (g >> 1)) ^ swz;
          *(uint2*)&plw[nf * 256 + u * 16 + bidx * 4 + (g & 1) * 2] = make_uint2(wA, wB);
        }
      }
      __builtin_amdgcn_s_setprio(1);
#pragma unroll
      for (int nf = 0; nf < 4; ++nf) {
        short8 pf = *(const short8*)&plw[nf * 256 + u * 16 + ((g ^ swz) << 2)];
        accO[0][nf] = __builtin_amdgcn_mfma_f32_16x16x32_bf16(vf0, pf, accO[0][nf], 0, 0, 0);
        accO[1][nf] = __builtin_amdgcn_mfma_f32_16x16x32_bf16(vf1, pf, accO[1][nf], 0, 0, 0);
      }
      __builtin_amdgcn_s_setprio(0);
    }
  }

#pragma unroll
  for (int nf = 0; nf < 4; ++nf) {
    lsum[nf] += __shfl_xor(lsum[nf], 16);
    lsum[nf] += __shfl_xor(lsum[nf], 32);
    float inv = 1.f / lsum[nf];
    int q = q0 + nf * 16 + u;
    int z = (((r >> 4) & 1) << 2) | ((q >> 6) & 3);
    int y = (((r >> 2) & 3) << 3) | ((q >> 3) & 7);
    int xx = ((r & 3) << 3) | (q & 7);
    int l = (z << 10) | (y << 5) | xx;
    u16* ob = &oreg[((size_t)(n * LL + l)) * CC + h * 32];
#pragma unroll
    for (int mf = 0; mf < 2; ++mf) {
      f32x4 o = mf ? accO[1][nf] : accO[0][nf];
      float a0 = o[0] * inv, a1 = o[1] * inv, a2 = o[2] * inv, a3 = o[3] * inv;
      unsigned w0, w1;
      asm("v_cvt_pk_bf16_f32 %0, %1, %2" : "=v"(w0) : "v"(a0), "v"(a1));
      asm("v_cvt_pk_bf16_f32 %0, %1, %2" : "=v"(w1) : "v"(a2), "v"(a3));
      *(uint2*)&ob[mf * 16 + g * 4] = make_uint2(w0, w1);
    }
  }
}

// ---------------- LEPE stencil -> atok bf16 K-blocked [kb][token][32] ----------------
__global__ __launch_bounds__(256) void k_lepe(const u16* __restrict__ oreg,
                                              const u16* __restrict__ vtok,
                                              const float* __restrict__ wT,
                                              u16* __restrict__ otok) {
  int vox = threadIdx.x >> 6;
  int b = blockIdx.x * 4 + vox;
  int l = b & (LL - 1);
  int lt = l >> 10, lh = (l >> 5) & 31, lw = l & 31;
  int c4 = (threadIdx.x & 63) * 4;
  const u16* vb = vtok + (size_t)b * CC + c4;
  float lx = 0.f, ly = 0.f, lz = 0.f, lww = 0.f;
#pragma unroll
  for (int dz = -1; dz <= 1; ++dz) {
#pragma unroll
    for (int dy = -1; dy <= 1; ++dy) {
#pragma unroll
      for (int dx = -1; dx <= 1; ++dx) {
        int z = lt + dz, y = lh + dy, xx = lw + dx;
        if (z >= 0 && z < 8 && y >= 0 && y < 32 && xx >= 0 && xx < 32) {
          int tap = ((dz + 1) * 3 + (dy + 1)) * 3 + (dx + 1);
          long off = (long)(dz * 1024 + dy * 32 + dx) * CC;
          float4 w4 = *(const float4*)&wT[tap * 256 + c4];
          u16x4 v4 = *(const u16x4*)&vb[off];
          lx = fmaf(w4.x, bf2f(v4[0]), lx);
          ly = fmaf(w4.y, bf2f(v4[1]), ly);
          lz = fmaf(w4.z, bf2f(v4[2]), lz);
          lww = fmaf(w4.w, bf2f(v4[3]), lww);
        }
      }
    }
  }
  u16x4 a4 = *(const u16x4*)&oreg[(size_t)b * CC + c4];
  size_t oaddr = (size_t)(c4 >> 5) * TBLK + (size_t)b * 32 + (c4 & 31);
  *(u16x4*)&otok[oaddr] =
      (u16x4){f2bf(bf2f(a4[0]) + lx), f2bf(bf2f(a4[1]) + ly),
              f2bf(bf2f(a4[2]) + lz), f2bf(bf2f(a4[3]) + lww)};
}

// ---------------- FUSED FFN, double-buffered h-tile (1 barrier/chunk) ----------------
#define GEMM1(hcv, acc1) { \
    const u16* Bp1 = w1T + (size_t)((hcv) * 128 + w * 32 + u) * 32 + g8; \
    _Pragma("unroll") \
    for (int kb = 0; kb < 8; ++kb) { \
      short8 a0 = *(const short8*)(ApS + (size_t)kb * TBLK); \
      short8 a1 = *(const short8*)(ApS + (size_t)kb * TBLK + 512); \
      short8 b0 = *(const short8*)(Bp1 + (size_t)kb * (1024 * 32)); \
      short8 bq = *(const short8*)(Bp1 + (size_t)kb * (1024 * 32) + 512); \
      acc1[0][0] = __builtin_amdgcn_mfma_f32_16x16x32_bf16(a0, b0, acc1[0][0], 0, 0, 0); \
      acc1[0][1] = __builtin_amdgcn_mfma_f32_16x16x32_bf16(a0, bq, acc1[0][1], 0, 0, 0); \
      acc1[1][0] = __builtin_amdgcn_mfma_f32_16x16x32_bf16(a1, b0, acc1[1][0], 0, 0, 0); \
      acc1[1][1] = __builtin_amdgcn_mfma_f32_16x16x32_bf16(a1, bq, acc1[1][1], 0, 0, 0); \
    } }

#define GELU_STORE(hcv, acc1, slab) { \
    _Pragma("unroll") \
    for (int i = 0; i < 2; ++i) { \
      _Pragma("unroll") \
      for (int reg = 0; reg < 4; ++reg) { \
        int tokl = i * 16 + g * 4 + reg; \
        _Pragma("unroll") \
        for (int j = 0; j < 2; ++j) { \
          int hh2 = j * 16 + u; \
          float z = acc1[i][j][reg] + b1[(hcv) * 128 + w * 32 + hh2]; \
          float z2 = z * z; \
          float ea = z * fmaf(z2, 0.1029431f, 2.3022078f); \
          float te = EXP2(ea); \
          float th = (te - 1.f) * __builtin_amdgcn_rcpf(te + 1.f); \
          float hz = 0.5f * z; \
          hl[slab][w][tokl][hh2] = f2bf(fmaf(hz, th, hz)); \
        } \
      } \
    } }

#define GEMM2(hcv, slab) { \
    _Pragma("unroll") \
    for (int kb2 = 0; kb2 < 4; ++kb2) { \
      const u16* a2 = Ap2 + (size_t)((hcv) * 4 + kb2) * (256 * 32); \
      short8 af[4], bfv[2]; \
      _Pragma("unroll") \
      for (int i = 0; i < 4; ++i) af[i] = *(const short8*)(a2 + i * 512); \
      _Pragma("unroll") \
      for (int j = 0; j < 2; ++j) bfv[j] = *(const short8*)&hl[slab][kb2][j * 16 + u][g8]; \
      _Pragma("unroll") \
      for (int i = 0; i < 4; ++i) \
        _Pragma("unroll") \
        for (int j = 0; j < 2; ++j) \
          acc2[i][j] = __builtin_amdgcn_mfma_f32_16x16x32_bf16(af[i], bfv[j], acc2[i][j], 0, 0, 0); \
    } }

__global__ __launch_bounds__(256) void k_gffn(const u16* __restrict__ sT, const u16* __restrict__ w1T,
                                              const u16* __restrict__ w2T,
                                              const float* __restrict__ b1, const float* __restrict__ b2,
                                              const float* __restrict__ scale, float* __restrict__ out) {
  __shared__ __align__(16) u16 hl[2][4][32][40];   // 2 slabs x 10 KB
  int m0 = blockIdx.x * 32;
  int w = threadIdx.x >> 6, lane = threadIdx.x & 63;
  int u = lane & 15, g = lane >> 4;
  int g8 = g * 8;
  f32x4 acc2[4][4] = {};

  const u16* ApS = sT + (size_t)(m0 + u) * 32 + g8;
  const u16* Ap2 = w2T + (size_t)(w * 64 + u) * 32 + g8;

  {
    f32x4 acc1[2][2] = {};
    GEMM1(0, acc1);
    GELU_STORE(0, acc1, 0);
  }
  __syncthreads();
#pragma unroll
  for (int hc = 0; hc < 7; ++hc) {
    f32x4 acc1[2][2] = {};
    GEMM1(hc + 1, acc1);            // global loads issue early, drain under GEMM2
    GEMM2(hc, hc & 1);              // reads current slab
    GELU_STORE(hc + 1, acc1, (hc + 1) & 1);  // writes other slab
    __syncthreads();
  }
  GEMM2(7, 1);

  // ---- epilogue: out[t][ch][l] += (acc2 + b2)*sc ----
  float sc = scale[0];
#pragma unroll
  for (int i = 0; i < 4; ++i) {
#pragma unroll
    for (int reg = 0; reg < 4; ++reg) {
      int ch = w * 64 + i * 16 + g * 4 + reg;
      float bb = b2[ch];
#pragma unroll
      for (int j = 0; j < 2; ++j) {
        int token = m0 + j * 16 + u;
        int t = token >> 13, l = token & (LL - 1);
        size_t oi = ((size_t)t * CC + ch) * LL + l;
        out[oi] += (acc2[i][j][reg] + bb) * sc;
      }
    }
  }
}

// ---------------- Wo GEMM, 4-wave split-K: out = x + (Wo^T a + bo)*sc, fused BN2 partials ----------------
__global__ __launch_bounds__(256) void k_gwo(const u16* __restrict__ woT, const u16* __restrict__ atok,
                                             const float* __restrict__ bias, const float* __restrict__ xin,
                                             const float* __restrict__ scale, float* __restrict__ out,
                                             float* __restrict__ psum, float* __restrict__ psq) {
  __shared__ f32x4 red[2][2][4][64];
  __shared__ float lsum[2][32], lsq[2][32];
  f32x4 acc[2][4] = {};
  int n0 = blockIdx.x * 128, m0 = blockIdx.y * 32;
  int w = threadIdx.x >> 6, lane = threadIdx.x & 63;
  int kh2 = w >> 1, wc = w & 1;
  mfma_core_w<2, 4, 128>(woT + (size_t)m0 * 32 + (size_t)kh2 * 4 * (256 * 32), 256 * 32,
                         atok + (size_t)n0 * 32 + (size_t)kh2 * 4 * TBLK, TBLK,
                         0, wc, acc);
  if (w >= 2) {
#pragma unroll
    for (int i = 0; i < 2; ++i)
#pragma unroll
      for (int j = 0; j < 4; ++j)
        red[w - 2][i][j][lane] = acc[i][j];
  }
  __syncthreads();
  if (w < 2) {
    int g = lane >> 4;
    float sc = scale[0];
#pragma unroll
    for (int i = 0; i < 2; ++i)
#pragma unroll
      for (int j = 0; j < 4; ++j)
        acc[i][j] += red[w][i][j][lane];
#pragma unroll
    for (int i = 0; i < 2; ++i) {
#pragma unroll
      for (int reg = 0; reg < 4; ++reg) {
        int ch = m0 + i * 16 + g * 4 + reg;
        float bb = bias[ch];
        float s = 0.f, q = 0.f;
#pragma unroll
        for (int j = 0; j < 4; ++j) {
          int token = n0 + wc * 64 + j * 16 + (lane & 15);
          int t = token >> 13, l = token & (LL - 1);
          size_t oi = ((size_t)t * CC + ch) * LL + l;
          float v = xin[oi] + (acc[i][j][reg] + bb) * sc;
          out[oi] = v;
          s += v; q += v * v;
        }
        s += __shfl_xor(s, 1); q += __shfl_xor(q, 1);
        s += __shfl_xor(s, 2); q += __shfl_xor(q, 2);
        s += __shfl_xor(s, 4); q += __shfl_xor(q, 4);
        s += __shfl_xor(s, 8); q += __shfl_xor(q, 8);
        if ((lane & 15) == 0) {
          lsum[wc][i * 16 + g * 4 + reg] = s;
          lsq[wc][i * 16 + g * 4 + reg] = q;
        }
      }
    }
  }
  __syncthreads();
  int tid = threadIdx.x;
  if (tid < 32) {
    psum[(m0 + tid) * 128 + blockIdx.x] = lsum[0][tid] + lsum[1][tid];
    psq[(m0 + tid) * 128 + blockIdx.x] = lsq[0][tid] + lsq[1][tid];
  }
}

extern "C" void kernel_launch(void* const* d_in, const int* in_sizes, int n_in,
                              void* d_out, int out_size, void* d_ws, size_t ws_size,
                              hipStream_t stream) {
  const float* x      = (const float*)d_in[0];
  const float* bn1_g  = (const float*)d_in[1];
  const float* bn1_b  = (const float*)d_in[2];
  const float* wqkv   = (const float*)d_in[3];
  const float* bqkv   = (const float*)d_in[4];
  const float* lepe_w = (const float*)d_in[5];
  const float* wo_w   = (const float*)d_in[6];
  const float* bo     = (const float*)d_in[7];
  const float* bn2_g  = (const float*)d_in[8];
  const float* bn2_b  = (const float*)d_in[9];
  const float* ffn_w1 = (const float*)d_in[10];
  const float* ffn_b1 = (const float*)d_in[11];
  const float* ffn_w2 = (const float*)d_in[12];
  const float* ffn_b2 = (const float*)d_in[13];
  const float* scale  = (const float*)d_in[14];
  float* out = (float*)d_out;

  float* ws    = (float*)d_ws;
  u16*   actT  = (u16*)(ws + 4194304);
  u16*   qhead = (u16*)(ws + 6291456);
  u16*   khead = (u16*)(ws + 8388608);
  u16*   vthead= (u16*)(ws + 10485760);
  u16*   vtok  = (u16*)(ws + 12582912);
  u16*   oreg  = (u16*)(ws + 16777216);
  u16*   wqkvT = (u16*)(ws + 20971520);
  u16*   w1T   = (u16*)(ws + 21069824);
  u16*   w2T   = (u16*)(ws + 21200896);
  u16*   woT   = (u16*)(ws + 21331968);
  float* sm    = ws + 21364736;
  float* mean1 = sm;
  float* istd1 = sm + 256;
  float* mean2 = sm + 512;
  float* istd2 = sm + 768;
  float* qm    = sm + 1024;
  float* km    = sm + 1024 + 16384;
  int*   idxb  = (int*)(sm + 1024 + 32768);
  float* wTlep = sm + 1024 + 32768 + 256;
  float* psum  = sm + 1024 + 32768 + 256 + 6912;
  float* psq   = psum + 32768;

  // fused weight transposes (bf16, K-blocked [kb][n][32]) + lepe wT
  k_trall<<<769, 256, 0, stream>>>(wqkv, ffn_w1, ffn_w2, wo_w, lepe_w,
                                   wqkvT, w1T, w2T, woT, wTlep);

  // ---- attention branch ----
  k_bnstats<<<256, 256, 0, stream>>>(x, mean1, istd1);
  k_lifT<<<dim3(256, 8), 256, 0, stream>>>(x, mean1, istd1, bn1_g, bn1_b, actT);
  k_gqkv<<<dim3(128, 6), 256, 0, stream>>>(actT, wqkvT, bqkv, qhead, khead, vthead, vtok);
  k_means<<<512, 256, 0, stream>>>(qhead, khead, qm, km);
  k_route<<<64, 256, 0, stream>>>(qm, km, idxb);
  k_attn_mfma<<<dim3(8, RR, 2), 256, 0, stream>>>(qhead, khead, vthead, idxb, oreg);
  k_lepe<<<4096, 256, 0, stream>>>(oreg, vtok, wTlep, actT);
  k_gwo<<<dim3(128, 8), 256, 0, stream>>>(woT, actT, bo, x, scale, out, psum, psq);

  // ---- FFN branch (fused GEMM1+GELU+GEMM2, double-buffered) ----
  k_bnfin<<<256, 128, 0, stream>>>(psum, psq, mean2, istd2);
  k_lifT<<<dim3(256, 8), 256, 0, stream>>>(out, mean2, istd2, bn2_g, bn2_b, actT);
  k_gffn<<<512, 256, 0, stream>>>(actT, w1T, w2T, ffn_b1, ffn_b2, scale, out);
}

// Round 17
// 184.883 us; speedup vs baseline: 1.0506x; 1.0506x over previous
//
#include <hip/hip_runtime.h>
#include <math.h>

#define CC 256
#define LL 8192
#define RR 32
#define PPP 256
#define NTOP 4
#define TOKS 16384
#define TBLK (TOKS * 32)   // per-kb stride for token-row operands

typedef unsigned short u16;
typedef __attribute__((ext_vector_type(8))) short short8;
typedef __attribute__((ext_vector_type(8))) unsigned short u16x8;
typedef __attribute__((ext_vector_type(4))) float f32x4;
typedef __attribute__((ext_vector_type(4))) unsigned short u16x4;

#if defined(__has_builtin)
#if __has_builtin(__builtin_amdgcn_exp2f)
#define EXP2(x) __builtin_amdgcn_exp2f(x)
#endif
#endif
#ifndef EXP2
#define EXP2(x) exp2f(x)
#endif

__device__ inline u16 f2bf(float f) {
  unsigned int b = __float_as_uint(f);
  unsigned int r = (b + 0x7FFFu + ((b >> 16) & 1u)) >> 16;
  return (u16)r;
}
__device__ inline float bf2f(u16 x) { return __uint_as_float(((unsigned int)x) << 16); }

// ---------------- finish BN2 stats from per-block partials (deterministic) ----------------
__global__ __launch_bounds__(128) void k_bnfin(const float* __restrict__ psum,
                                               const float* __restrict__ psq,
                                               float* __restrict__ mean,
                                               float* __restrict__ istd) {
  int c = blockIdx.x;
  int tid = threadIdx.x;
  __shared__ float rs[128], rq[128];
  rs[tid] = psum[c * 128 + tid];
  rq[tid] = psq[c * 128 + tid];
  __syncthreads();
  for (int off = 64; off > 0; off >>= 1) {
    if (tid < off) { rs[tid] += rs[tid + off]; rq[tid] += rq[tid + off]; }
    __syncthreads();
  }
  if (tid == 0) {
    float m = rs[0] * (1.f / 16384.f);
    float var = rq[0] * (1.f / 16384.f) - m * m;
    mean[c] = m;
    istd[c] = rsqrtf(var + 1e-5f);
  }
}

// ---------------- fused BN + 2-step LIF + transpose -> actT bf16 K-blocked [kb][token][32] ----------------
__global__ __launch_bounds__(256) void k_lifT(const float* __restrict__ xin,
                                              const float* __restrict__ mean,
                                              const float* __restrict__ istd,
                                              const float* __restrict__ g,
                                              const float* __restrict__ b,
                                              u16* __restrict__ actT) {
  __shared__ float t0[32][33], t1[32][33];
  int l0 = blockIdx.x * 32, c0 = blockIdx.y * 32;
  int tx = threadIdx.x & 31, ty = threadIdx.x >> 5;
  for (int i = 0; i < 32; i += 8) {
    int c = c0 + ty + i;
    float m = mean[c], is = istd[c], gg = g[c], bb = b[c];
    float x0 = xin[(size_t)c * LL + l0 + tx];
    float x1 = xin[(size_t)(CC + c) * LL + l0 + tx];
    float y0 = gg * (x0 - m) * is + bb;
    float y1 = gg * (x1 - m) * is + bb;
    float v = y0 * 0.5f;
    float s0 = (v >= 1.f) ? 1.f : 0.f;
    v -= s0;
    v += (y1 - v) * 0.5f;
    float s1 = (v >= 1.f) ? 1.f : 0.f;
    t0[ty + i][tx] = s0;
    t1[ty + i][tx] = s1;
  }
  __syncthreads();
  size_t kb = (size_t)(c0 >> 5) * TBLK;
  for (int i = 0; i < 32; i += 8) {
    int l = l0 + ty + i;
    actT[kb + (size_t)l * 32 + tx] = f2bf(t0[tx][ty + i]);
    actT[kb + (size_t)(LL + l) * 32 + tx] = f2bf(t1[tx][ty + i]);
  }
}

// ---------------- fused: weight transposes + BN1 stats (independent inputs) ----------------
__device__ inline void tr_tile(const float* __restrict__ in, u16* __restrict__ out,
                               int C, int c0, int r0) {
  __shared__ float t[32][33];
  int tx = threadIdx.x & 31, ty = threadIdx.x >> 5;
  for (int i = 0; i < 32; i += 8)
    t[ty + i][tx] = in[(size_t)(r0 + ty + i) * C + c0 + tx];
  __syncthreads();
  size_t kb = (size_t)(r0 >> 5) * C * 32;
  for (int i = 0; i < 32; i += 8)
    out[kb + (size_t)(c0 + ty + i) * 32 + tx] = f2bf(t[tx][ty + i]);
}

__global__ __launch_bounds__(256) void k_trall(const float* __restrict__ wqkv,
                                               const float* __restrict__ w1,
                                               const float* __restrict__ w2,
                                               const float* __restrict__ wo,
                                               const float* __restrict__ lep,
                                               const float* __restrict__ x,
                                               u16* __restrict__ wqkvT, u16* __restrict__ w1T,
                                               u16* __restrict__ w2T, u16* __restrict__ woT,
                                               float* __restrict__ wTlep,
                                               float* __restrict__ mean1, float* __restrict__ istd1) {
  int b = blockIdx.x;
  if (b < 192) {
    tr_tile(wqkv, wqkvT, 768, (b % 24) * 32, (b / 24) * 32);
  } else if (b < 448) {
    int i = b - 192;
    tr_tile(w1, w1T, 1024, (i % 32) * 32, (i / 32) * 32);
  } else if (b < 704) {
    int i = b - 448;
    tr_tile(w2, w2T, 256, (i % 8) * 32, (i / 8) * 32);
  } else if (b < 768) {
    int i = b - 704;
    tr_tile(wo, woT, 256, (i % 8) * 32, (i / 8) * 32);
  } else if (b == 768) {
    int c = threadIdx.x;
    for (int tap = 0; tap < 27; ++tap) wTlep[tap * 256 + c] = lep[c * 27 + tap];
  } else {
    // BN1 stats for channel (b - 769)
    int c = b - 769, tid = threadIdx.x;
    float s = 0.f, sq = 0.f;
    for (int i = tid; i < 2 * LL / 4; i += 256) {
      int t = i >> 11, l4 = (i & 2047) * 4;
      float4 v = *(const float4*)&x[(size_t)(t * CC + c) * LL + l4];
      s += (v.x + v.y) + (v.z + v.w);
      sq += (v.x * v.x + v.y * v.y) + (v.z * v.z + v.w * v.w);
    }
    __shared__ float rs[256], rq[256];
    rs[tid] = s; rq[tid] = sq;
    __syncthreads();
    for (int off = 128; off > 0; off >>= 1) {
      if (tid < off) { rs[tid] += rs[tid + off]; rq[tid] += rq[tid + off]; }
      __syncthreads();
    }
    if (tid == 0) {
      float m = rs[0] * (1.f / (2 * LL));
      float var = rq[0] * (1.f / (2 * LL)) - m * m;
      mean1[c] = m;
      istd1[c] = rsqrtf(var + 1e-5f);
    }
  }
}

// ---------------- MFMA core, K-blocked operands + register prefetch; explicit wave coords ----------------
template<int MR, int NR, int KTOT>
__device__ inline void mfma_core_w(const u16* __restrict__ A0, int sAb,
                                   const u16* __restrict__ B0, int sBb,
                                   int wr, int wc, f32x4 acc[MR][NR]) {
  int lane = threadIdx.x & 63;
  int u = lane & 15;
  int g8 = (lane >> 4) * 8;
  const u16* Ap = A0 + (wr * MR * 16 + u) * 32 + g8;
  const u16* Bp = B0 + (wc * NR * 16 + u) * 32 + g8;
  constexpr int NKB = KTOT >> 5;
  short8 aA[MR], bA[NR], aB[MR], bB[NR];
#pragma unroll
  for (int i = 0; i < MR; ++i) aA[i] = *(const short8*)(Ap + i * 512);
#pragma unroll
  for (int j = 0; j < NR; ++j) bA[j] = *(const short8*)(Bp + j * 512);
#pragma unroll
  for (int kb = 0; kb < NKB; kb += 2) {
    if (kb + 1 < NKB) {
#pragma unroll
      for (int i = 0; i < MR; ++i) aB[i] = *(const short8*)(Ap + (size_t)(kb + 1) * sAb + i * 512);
#pragma unroll
      for (int j = 0; j < NR; ++j) bB[j] = *(const short8*)(Bp + (size_t)(kb + 1) * sBb + j * 512);
    }
#pragma unroll
    for (int i = 0; i < MR; ++i)
#pragma unroll
      for (int j = 0; j < NR; ++j)
        acc[i][j] = __builtin_amdgcn_mfma_f32_16x16x32_bf16(aA[i], bA[j], acc[i][j], 0, 0, 0);
    if (kb + 2 < NKB) {
#pragma unroll
      for (int i = 0; i < MR; ++i) aA[i] = *(const short8*)(Ap + (size_t)(kb + 2) * sAb + i * 512);
#pragma unroll
      for (int j = 0; j < NR; ++j) bA[j] = *(const short8*)(Bp + (size_t)(kb + 2) * sBb + j * 512);
    }
    if (kb + 1 < NKB) {
#pragma unroll
      for (int i = 0; i < MR; ++i)
#pragma unroll
        for (int j = 0; j < NR; ++j)
          acc[i][j] = __builtin_amdgcn_mfma_f32_16x16x32_bf16(aB[i], bB[j], acc[i][j], 0, 0, 0);
    }
  }
}

// ---------------- qkv GEMM -> bf16 per-head q(scaled)/k, transposed v (u16x4 packed); bf16 v token-major ----------------
__global__ __launch_bounds__(256) void k_gqkv(const u16* __restrict__ spkT, const u16* __restrict__ wT,
                                              const float* __restrict__ bias,
                                              u16* __restrict__ qh, u16* __restrict__ kh,
                                              u16* __restrict__ vt, u16* __restrict__ vtok) {
  f32x4 acc[4][4] = {};
  int m0 = blockIdx.x * 128, n0 = blockIdx.y * 128;
  int w = threadIdx.x >> 6;
  mfma_core_w<4, 4, 256>(spkT + (size_t)m0 * 32, TBLK, wT + (size_t)n0 * 32, 768 * 32,
                         w >> 1, w & 1, acc);
  int lane = threadIdx.x & 63;
  int wr = w >> 1, wc = w & 1;
  int u = lane & 15;
  const float QSC = 0.255034865f;   // 32^-0.5 * log2(e)
#pragma unroll
  for (int i = 0; i < 4; ++i) {
    int token0 = m0 + wr * 64 + i * 16 + (lane >> 4) * 4;
    int l = token0 & (LL - 1), nb = token0 >> 13;
    int lt = l >> 10, lh = (l >> 5) & 31, lw = l & 31;
    int r = ((lt >> 2) * 4 + (lh >> 3)) * 4 + (lw >> 3);
    int p0 = ((lt & 3) * 8 + (lh & 7)) * 8 + (lw & 7);
    int nr = nb * RR + r;
#pragma unroll
    for (int j = 0; j < 4; ++j) {
      int ch = n0 + wc * 64 + j * 16 + u;
      int which = ch >> 8, c = ch & 255;
      int hh = c >> 5, dh = c & 31;
      size_t hb = ((size_t)nr * 8 + hh) * 8192;
      float bb = bias[ch];
      if (which == 0) {
#pragma unroll
        for (int reg = 0; reg < 4; ++reg)
          qh[hb + (p0 + reg) * 32 + dh] = f2bf((acc[i][j][reg] + bb) * QSC);
      } else if (which == 1) {
#pragma unroll
        for (int reg = 0; reg < 4; ++reg)
          kh[hb + (p0 + reg) * 32 + dh] = f2bf(acc[i][j][reg] + bb);
      } else {
        u16x4 pk;
#pragma unroll
        for (int reg = 0; reg < 4; ++reg) {
          u16 vb = f2bf(acc[i][j][reg] + bb);
          pk[reg] = vb;
          vtok[(size_t)(token0 + reg) * CC + c] = vb;
        }
        *(u16x4*)&vt[hb + dh * 256 + p0] = pk;
      }
    }
  }
}

// ---------------- region means: block per (nr, h) ----------------
__global__ __launch_bounds__(256) void k_means(const u16* __restrict__ qh, const u16* __restrict__ kh,
                                               float* __restrict__ qm, float* __restrict__ km) {
  int nrh = blockIdx.x;
  int nr = nrh >> 3, h = nrh & 7;
  int tid = threadIdx.x;
  int dh = tid & 31, pg = tid >> 5;
  size_t base = (size_t)nrh * 8192;
  float sq = 0.f, sk = 0.f;
  for (int p = pg * 32; p < pg * 32 + 32; ++p) {
    sq += bf2f(qh[base + p * 32 + dh]);
    sk += bf2f(kh[base + p * 32 + dh]);
  }
  __shared__ float rq[256], rk[256];
  rq[tid] = sq; rk[tid] = sk;
  __syncthreads();
  if (pg == 0) {
#pragma unroll
    for (int g = 1; g < 8; ++g) { sq += rq[g * 32 + dh]; sk += rk[g * 32 + dh]; }
    qm[nr * 256 + h * 32 + dh] = sq * (1.f / 256);
    km[nr * 256 + h * 32 + dh] = sk * (1.f / 256);
  }
}

// ---------------- routing top-4: 8 lanes per candidate region ----------------
__global__ __launch_bounds__(256) void k_route(const float* __restrict__ qm,
                                               const float* __restrict__ km,
                                               int* __restrict__ idx) {
  int nr = blockIdx.x;
  int n = nr >> 5;
  int tid = threadIdx.x;
  int s = tid >> 3, cg = tid & 7;
  const float* qrow = qm + nr * CC;
  const float* krow = km + (n * RR + s) * CC;
  float sum = 0.f;
  for (int c = cg * 32; c < cg * 32 + 32; ++c) sum += qrow[c] * krow[c];
  sum += __shfl_xor(sum, 1);
  sum += __shfl_xor(sum, 2);
  sum += __shfl_xor(sum, 4);
  __shared__ float ar[32];
  if (cg == 0) ar[s] = sum;
  __syncthreads();
  if (tid == 0) {
    for (int t = 0; t < NTOP; ++t) {
      float best = -1e30f; int bi = 0;
      for (int ss = 0; ss < 32; ++ss)
        if (ar[ss] > best) { best = ar[ss]; bi = ss; }
      ar[bi] = -1e30f;
      idx[nr * NTOP + t] = bi;
    }
  }
}

// ---------------- MFMA flash attention: block (h, r, n), 4 waves x 64 q-rows ----------------
__global__ __launch_bounds__(256) void k_attn_mfma(const u16* __restrict__ qh,
                                                   const u16* __restrict__ kh,
                                                   const u16* __restrict__ vt,
                                                   const int* __restrict__ idx,
                                                   u16* __restrict__ oreg) {
  int h = blockIdx.x, r = blockIdx.y, n = blockIdx.z;
  int nr = n * RR + r;
  int lane = threadIdx.x & 63;
  int w = threadIdx.x >> 6;
  int u = lane & 15, g = lane >> 4;
  int swz = (u >> 1) & 3;
  __shared__ __align__(16) unsigned pl[4096];
  unsigned* plw = &pl[w * 1024];

  const u16* qb = qh + ((size_t)nr * 8 + h) * 8192;
  int q0 = w * 64;
  short8 qf[4];
#pragma unroll
  for (int f = 0; f < 4; ++f)
    qf[f] = *(const short8*)(qb + (size_t)(q0 + f * 16 + u) * 32 + g * 8);

  f32x4 accO[2][4] = {};
  float lsum[4] = {0.f, 0.f, 0.f, 0.f};
  const int* idxp = &idx[nr * NTOP];

  for (int ri = 0; ri < NTOP; ++ri) {
    int reg = idxp[ri];
    size_t rb = ((size_t)(n * RR + reg) * 8 + h) * 8192;
#pragma unroll 2
    for (int t = 0; t < 8; ++t) {
      int pb = t * 32;
      short8 kf0 = *(const short8*)(kh + rb + (size_t)(pb + u) * 32 + g * 8);
      short8 kf1 = *(const short8*)(kh + rb + (size_t)(pb + 16 + u) * 32 + g * 8);
      short8 vf0 = *(const short8*)(vt + rb + (size_t)u * 256 + pb + g * 8);
      short8 vf1 = *(const short8*)(vt + rb + (size_t)(16 + u) * 256 + pb + g * 8);

      f32x4 s0[4], s1[4];
      __builtin_amdgcn_s_setprio(1);
#pragma unroll
      for (int nf = 0; nf < 4; ++nf) {
        s0[nf] = __builtin_amdgcn_mfma_f32_16x16x32_bf16(kf0, qf[nf], (f32x4){0.f, 0.f, 0.f, 0.f}, 0, 0, 0);
        s1[nf] = __builtin_amdgcn_mfma_f32_16x16x32_bf16(kf1, qf[nf], (f32x4){0.f, 0.f, 0.f, 0.f}, 0, 0, 0);
      }
      __builtin_amdgcn_s_setprio(0);
#pragma unroll
      for (int nf = 0; nf < 4; ++nf) {
#pragma unroll
        for (int mf = 0; mf < 2; ++mf) {
          f32x4 sv = mf ? s1[nf] : s0[nf];
          float p0 = EXP2(sv[0]);
          float p1 = EXP2(sv[1]);
          float p2 = EXP2(sv[2]);
          float p3 = EXP2(sv[3]);
          lsum[nf] += (p0 + p1) + (p2 + p3);
          unsigned wA, wB;
          asm("v_cvt_pk_bf16_f32 %0, %1, %2" : "=v"(wA) : "v"(p0), "v"(p1));
          asm("v_cvt_pk_bf16_f32 %0, %1, %2" : "=v"(wB) : "v"(p2), "v"(p3));
          int bidx = (mf * 2 + (g >> 1)) ^ swz;
          *(uint2*)&plw[nf * 256 + u * 16 + bidx * 4 + (g & 1) * 2] = make_uint2(wA, wB);
        }
      }
      __builtin_amdgcn_s_setprio(1);
#pragma unroll
      for (int nf = 0; nf < 4; ++nf) {
        short8 pf = *(const short8*)&plw[nf * 256 + u * 16 + ((g ^ swz) << 2)];
        accO[0][nf] = __builtin_amdgcn_mfma_f32_16x16x32_bf16(vf0, pf, accO[0][nf], 0, 0, 0);
        accO[1][nf] = __builtin_amdgcn_mfma_f32_16x16x32_bf16(vf1, pf, accO[1][nf], 0, 0, 0);
      }
      __builtin_amdgcn_s_setprio(0);
    }
  }

#pragma unroll
  for (int nf = 0; nf < 4; ++nf) {
    lsum[nf] += __shfl_xor(lsum[nf], 16);
    lsum[nf] += __shfl_xor(lsum[nf], 32);
    float inv = 1.f / lsum[nf];
    int q = q0 + nf * 16 + u;
    int z = (((r >> 4) & 1) << 2) | ((q >> 6) & 3);
    int y = (((r >> 2) & 3) << 3) | ((q >> 3) & 7);
    int xx = ((r & 3) << 3) | (q & 7);
    int l = (z << 10) | (y << 5) | xx;
    u16* ob = &oreg[((size_t)(n * LL + l)) * CC + h * 32];
#pragma unroll
    for (int mf = 0; mf < 2; ++mf) {
      f32x4 o = mf ? accO[1][nf] : accO[0][nf];
      float a0 = o[0] * inv, a1 = o[1] * inv, a2 = o[2] * inv, a3 = o[3] * inv;
      unsigned w0, w1;
      asm("v_cvt_pk_bf16_f32 %0, %1, %2" : "=v"(w0) : "v"(a0), "v"(a1));
      asm("v_cvt_pk_bf16_f32 %0, %1, %2" : "=v"(w1) : "v"(a2), "v"(a3));
      *(uint2*)&ob[mf * 16 + g * 4] = make_uint2(w0, w1);
    }
  }
}

// ---------------- LEPE stencil -> atok bf16 K-blocked [kb][token][32] ----------------
__global__ __launch_bounds__(256) void k_lepe(const u16* __restrict__ oreg,
                                              const u16* __restrict__ vtok,
                                              const float* __restrict__ wT,
                                              u16* __restrict__ otok) {
  int vox = threadIdx.x >> 6;
  int b = blockIdx.x * 4 + vox;
  int l = b & (LL - 1);
  int lt = l >> 10, lh = (l >> 5) & 31, lw = l & 31;
  int c4 = (threadIdx.x & 63) * 4;
  const u16* vb = vtok + (size_t)b * CC + c4;
  float lx = 0.f, ly = 0.f, lz = 0.f, lww = 0.f;
#pragma unroll
  for (int dz = -1; dz <= 1; ++dz) {
#pragma unroll
    for (int dy = -1; dy <= 1; ++dy) {
#pragma unroll
      for (int dx = -1; dx <= 1; ++dx) {
        int z = lt + dz, y = lh + dy, xx = lw + dx;
        if (z >= 0 && z < 8 && y >= 0 && y < 32 && xx >= 0 && xx < 32) {
          int tap = ((dz + 1) * 3 + (dy + 1)) * 3 + (dx + 1);
          long off = (long)(dz * 1024 + dy * 32 + dx) * CC;
          float4 w4 = *(const float4*)&wT[tap * 256 + c4];
          u16x4 v4 = *(const u16x4*)&vb[off];
          lx = fmaf(w4.x, bf2f(v4[0]), lx);
          ly = fmaf(w4.y, bf2f(v4[1]), ly);
          lz = fmaf(w4.z, bf2f(v4[2]), lz);
          lww = fmaf(w4.w, bf2f(v4[3]), lww);
        }
      }
    }
  }
  u16x4 a4 = *(const u16x4*)&oreg[(size_t)b * CC + c4];
  size_t oaddr = (size_t)(c4 >> 5) * TBLK + (size_t)b * 32 + (c4 & 31);
  *(u16x4*)&otok[oaddr] =
      (u16x4){f2bf(bf2f(a4[0]) + lx), f2bf(bf2f(a4[1]) + ly),
              f2bf(bf2f(a4[2]) + lz), f2bf(bf2f(a4[3]) + lww)};
}

// ---------------- FUSED FFN (round-15 proven single-buffer version) ----------------
__global__ __launch_bounds__(256) void k_gffn(const u16* __restrict__ sT, const u16* __restrict__ w1T,
                                              const u16* __restrict__ w2T,
                                              const float* __restrict__ b1, const float* __restrict__ b2,
                                              const float* __restrict__ scale, float* __restrict__ out) {
  __shared__ __align__(16) u16 hl[4][32][40];   // [kb2][tok][32+8 pad] = 10 KB
  int m0 = blockIdx.x * 32;
  int w = threadIdx.x >> 6, lane = threadIdx.x & 63;
  int u = lane & 15, g = lane >> 4;
  int g8 = g * 8;
  f32x4 acc2[4][4] = {};

  const u16* ApS = sT + (size_t)(m0 + u) * 32 + g8;
  const u16* Ap2 = w2T + (size_t)(w * 64 + u) * 32 + g8;

  for (int hc = 0; hc < 8; ++hc) {
    f32x4 acc1[2][2] = {};
    const u16* Bp1 = w1T + (size_t)(hc * 128 + w * 32 + u) * 32 + g8;
#pragma unroll
    for (int kb = 0; kb < 8; ++kb) {
      short8 a0 = *(const short8*)(ApS + (size_t)kb * TBLK);
      short8 a1 = *(const short8*)(ApS + (size_t)kb * TBLK + 512);
      short8 b0 = *(const short8*)(Bp1 + (size_t)kb * (1024 * 32));
      short8 bq = *(const short8*)(Bp1 + (size_t)kb * (1024 * 32) + 512);
      acc1[0][0] = __builtin_amdgcn_mfma_f32_16x16x32_bf16(a0, b0, acc1[0][0], 0, 0, 0);
      acc1[0][1] = __builtin_amdgcn_mfma_f32_16x16x32_bf16(a0, bq, acc1[0][1], 0, 0, 0);
      acc1[1][0] = __builtin_amdgcn_mfma_f32_16x16x32_bf16(a1, b0, acc1[1][0], 0, 0, 0);
      acc1[1][1] = __builtin_amdgcn_mfma_f32_16x16x32_bf16(a1, bq, acc1[1][1], 0, 0, 0);
    }
    __syncthreads();
#pragma unroll
    for (int i = 0; i < 2; ++i) {
#pragma unroll
      for (int reg = 0; reg < 4; ++reg) {
        int tokl = i * 16 + g * 4 + reg;
#pragma unroll
        for (int j = 0; j < 2; ++j) {
          int hh2 = j * 16 + u;
          float z = acc1[i][j][reg] + b1[hc * 128 + w * 32 + hh2];
          float z2 = z * z;
          float ea = z * fmaf(z2, 0.1029431f, 2.3022078f);
          float t = EXP2(ea);
          float th = (t - 1.f) * __builtin_amdgcn_rcpf(t + 1.f);
          float hz = 0.5f * z;
          hl[w][tokl][hh2] = f2bf(fmaf(hz, th, hz));
        }
      }
    }
    __syncthreads();
#pragma unroll
    for (int kb2 = 0; kb2 < 4; ++kb2) {
      const u16* a2 = Ap2 + (size_t)(hc * 4 + kb2) * (256 * 32);
      short8 af[4], bfv[2];
#pragma unroll
      for (int i = 0; i < 4; ++i) af[i] = *(const short8*)(a2 + i * 512);
#pragma unroll
      for (int j = 0; j < 2; ++j) bfv[j] = *(const short8*)&hl[kb2][j * 16 + u][g8];
#pragma unroll
      for (int i = 0; i < 4; ++i)
#pragma unroll
        for (int j = 0; j < 2; ++j)
          acc2[i][j] = __builtin_amdgcn_mfma_f32_16x16x32_bf16(af[i], bfv[j], acc2[i][j], 0, 0, 0);
    }
  }

  float sc = scale[0];
#pragma unroll
  for (int i = 0; i < 4; ++i) {
#pragma unroll
    for (int reg = 0; reg < 4; ++reg) {
      int ch = w * 64 + i * 16 + g * 4 + reg;
      float bb = b2[ch];
#pragma unroll
      for (int j = 0; j < 2; ++j) {
        int token = m0 + j * 16 + u;
        int t = token >> 13, l = token & (LL - 1);
        size_t oi = ((size_t)t * CC + ch) * LL + l;
        out[oi] += (acc2[i][j][reg] + bb) * sc;
      }
    }
  }
}

// ---------------- Wo GEMM, 4-wave split-K: out = x + (Wo^T a + bo)*sc, fused BN2 partials ----------------
__global__ __launch_bounds__(256) void k_gwo(const u16* __restrict__ woT, const u16* __restrict__ atok,
                                             const float* __restrict__ bias, const float* __restrict__ xin,
                                             const float* __restrict__ scale, float* __restrict__ out,
                                             float* __restrict__ psum, float* __restrict__ psq) {
  __shared__ f32x4 red[2][2][4][64];
  __shared__ float lsum[2][32], lsq[2][32];
  f32x4 acc[2][4] = {};
  int n0 = blockIdx.x * 128, m0 = blockIdx.y * 32;
  int w = threadIdx.x >> 6, lane = threadIdx.x & 63;
  int kh2 = w >> 1, wc = w & 1;
  mfma_core_w<2, 4, 128>(woT + (size_t)m0 * 32 + (size_t)kh2 * 4 * (256 * 32), 256 * 32,
                         atok + (size_t)n0 * 32 + (size_t)kh2 * 4 * TBLK, TBLK,
                         0, wc, acc);
  if (w >= 2) {
#pragma unroll
    for (int i = 0; i < 2; ++i)
#pragma unroll
      for (int j = 0; j < 4; ++j)
        red[w - 2][i][j][lane] = acc[i][j];
  }
  __syncthreads();
  if (w < 2) {
    int g = lane >> 4;
    float sc = scale[0];
#pragma unroll
    for (int i = 0; i < 2; ++i)
#pragma unroll
      for (int j = 0; j < 4; ++j)
        acc[i][j] += red[w][i][j][lane];
#pragma unroll
    for (int i = 0; i < 2; ++i) {
#pragma unroll
      for (int reg = 0; reg < 4; ++reg) {
        int ch = m0 + i * 16 + g * 4 + reg;
        float bb = bias[ch];
        float s = 0.f, q = 0.f;
#pragma unroll
        for (int j = 0; j < 4; ++j) {
          int token = n0 + wc * 64 + j * 16 + (lane & 15);
          int t = token >> 13, l = token & (LL - 1);
          size_t oi = ((size_t)t * CC + ch) * LL + l;
          float v = xin[oi] + (acc[i][j][reg] + bb) * sc;
          out[oi] = v;
          s += v; q += v * v;
        }
        s += __shfl_xor(s, 1); q += __shfl_xor(q, 1);
        s += __shfl_xor(s, 2); q += __shfl_xor(q, 2);
        s += __shfl_xor(s, 4); q += __shfl_xor(q, 4);
        s += __shfl_xor(s, 8); q += __shfl_xor(q, 8);
        if ((lane & 15) == 0) {
          lsum[wc][i * 16 + g * 4 + reg] = s;
          lsq[wc][i * 16 + g * 4 + reg] = q;
        }
      }
    }
  }
  __syncthreads();
  int tid = threadIdx.x;
  if (tid < 32) {
    psum[(m0 + tid) * 128 + blockIdx.x] = lsum[0][tid] + lsum[1][tid];
    psq[(m0 + tid) * 128 + blockIdx.x] = lsq[0][tid] + lsq[1][tid];
  }
}

extern "C" void kernel_launch(void* const* d_in, const int* in_sizes, int n_in,
                              void* d_out, int out_size, void* d_ws, size_t ws_size,
                              hipStream_t stream) {
  const float* x      = (const float*)d_in[0];
  const float* bn1_g  = (const float*)d_in[1];
  const float* bn1_b  = (const float*)d_in[2];
  const float* wqkv   = (const float*)d_in[3];
  const float* bqkv   = (const float*)d_in[4];
  const float* lepe_w = (const float*)d_in[5];
  const float* wo_w   = (const float*)d_in[6];
  const float* bo     = (const float*)d_in[7];
  const float* bn2_g  = (const float*)d_in[8];
  const float* bn2_b  = (const float*)d_in[9];
  const float* ffn_w1 = (const float*)d_in[10];
  const float* ffn_b1 = (const float*)d_in[11];
  const float* ffn_w2 = (const float*)d_in[12];
  const float* ffn_b2 = (const float*)d_in[13];
  const float* scale  = (const float*)d_in[14];
  float* out = (float*)d_out;

  float* ws    = (float*)d_ws;
  u16*   actT  = (u16*)(ws + 4194304);
  u16*   qhead = (u16*)(ws + 6291456);
  u16*   khead = (u16*)(ws + 8388608);
  u16*   vthead= (u16*)(ws + 10485760);
  u16*   vtok  = (u16*)(ws + 12582912);
  u16*   oreg  = (u16*)(ws + 16777216);
  u16*   wqkvT = (u16*)(ws + 20971520);
  u16*   w1T   = (u16*)(ws + 21069824);
  u16*   w2T   = (u16*)(ws + 21200896);
  u16*   woT   = (u16*)(ws + 21331968);
  float* sm    = ws + 21364736;
  float* mean1 = sm;
  float* istd1 = sm + 256;
  float* mean2 = sm + 512;
  float* istd2 = sm + 768;
  float* qm    = sm + 1024;
  float* km    = sm + 1024 + 16384;
  int*   idxb  = (int*)(sm + 1024 + 32768);
  float* wTlep = sm + 1024 + 32768 + 256;
  float* psum  = sm + 1024 + 32768 + 256 + 6912;
  float* psq   = psum + 32768;

  // fused: weight transposes + lepe wT + BN1 stats (independent inputs, one dispatch)
  k_trall<<<1025, 256, 0, stream>>>(wqkv, ffn_w1, ffn_w2, wo_w, lepe_w, x,
                                    wqkvT, w1T, w2T, woT, wTlep, mean1, istd1);

  // ---- attention branch ----
  k_lifT<<<dim3(256, 8), 256, 0, stream>>>(x, mean1, istd1, bn1_g, bn1_b, actT);
  k_gqkv<<<dim3(128, 6), 256, 0, stream>>>(actT, wqkvT, bqkv, qhead, khead, vthead, vtok);
  k_means<<<512, 256, 0, stream>>>(qhead, khead, qm, km);
  k_route<<<64, 256, 0, stream>>>(qm, km, idxb);
  k_attn_mfma<<<dim3(8, RR, 2), 256, 0, stream>>>(qhead, khead, vthead, idxb, oreg);
  k_lepe<<<4096, 256, 0, stream>>>(oreg, vtok, wTlep, actT);
  k_gwo<<<dim3(128, 8), 256, 0, stream>>>(woT, actT, bo, x, scale, out, psum, psq);

  // ---- FFN branch (fused GEMM1+GELU+GEMM2) ----
  k_bnfin<<<256, 128, 0, stream>>>(psum, psq, mean2, istd2);
  k_lifT<<<dim3(256, 8), 256, 0, stream>>>(out, mean2, istd2, bn2_g, bn2_b, actT);
  k_gffn<<<512, 256, 0, stream>>>(actT, w1T, w2T, ffn_b1, ffn_b2, scale, out);
}